// Round 5
// baseline (2122.161 us; speedup 1.0000x reference)
//
#include <hip/hip_runtime.h>

#define Bn   32
#define Cn   64
#define Ln   4096
#define Nn   (Bn*Cn*Ln)      // 8388608
#define FLn  8
#define MIDn 16
#define TILE3 64
#define NT   128             // ODE output positions per block (tile rows = NT+16)

typedef __bf16 bf16_t;
typedef bf16_t bf16x4 __attribute__((ext_vector_type(4)));
typedef bf16_t bf16x8 __attribute__((ext_vector_type(8)));
typedef float  f32x16 __attribute__((ext_vector_type(16)));

__device__ __forceinline__ float tanh_fast(float x) {
    float ax = fabsf(x);
    float t  = __expf(-2.0f * ax);
    float r  = __fmaf_rn(-2.0f, __fdividef(t, 1.0f + t), 1.0f);
    return copysignf(r, x);
}
__device__ __forceinline__ float gelu_fast(float x) {
    float x3 = x * x * x;
    float u  = 0.7978845608028654f * __fmaf_rn(0.044715f, x3, x);
    return 0.5f * x * (1.0f + tanh_fast(u));
}
__device__ __forceinline__ float sigmoid_f(float x) {
    return 1.0f / (1.0f + __expf(-x));
}

// ---------------- weight prep: MFMA A-frags + gate/att transposes ----------------
__global__ __launch_bounds__(256) void prep_weights(
    const float* __restrict__ w1, const float* __restrict__ w2,
    const float* __restrict__ gw, const float* __restrict__ aw2,
    bf16_t* __restrict__ w1f, bf16_t* __restrict__ w2f,
    float* __restrict__ gwt, float* __restrict__ aw2t)
{
    int idx = blockIdx.x*256 + threadIdx.x;
    if (idx < 1536) {
        int lane = idx & 63;
        int f  = (idx >> 6) % 12;
        int mt = (idx >> 6) / 12;
        int tau = f >> 2, ks = f & 3;
        int oc = mt*32 + (lane & 31);
        int c0 = ks*16 + (lane >> 5)*8;
        #pragma unroll
        for (int e = 0; e < 8; ++e) {
            int c = c0 + e;
            w1f[idx*8 + e] = (bf16_t)w1[oc*192 + c*3 + tau];
            w2f[idx*8 + e] = (bf16_t)w2[oc*192 + c*3 + tau];
        }
    }
    if (idx < 3*64*192) {
        int lvl = idx / 12288, rem = idx % 12288;
        int oc = rem / 192, r = rem % 192;
        gwt[lvl*12288 + r*64 + oc] = gw[idx];
    }
    if (idx < 2*64*16) {
        int lvl = idx / 1024, rem = idx % 1024;
        int oc = rem / 16, mm = rem % 16;
        aw2t[lvl*1024 + mm*64 + oc] = aw2[idx];
    }
}

// ---------------- fused full-RK4-step kernel (v2) ----------------
// 2 LDS buffers (ZC state, HT intermediate), granule-8 swizzle, b128 frag reads,
// read-clamp boundary semantics, fp32 global z0 base.
// Tile coord p in [0,144): l = l0-8+p. Regions per eval i:
//   h rows [2i+1, 143-2i), k rows [2i+2, 142-2i); outputs p in [8,136).
// Edge blocks: read-clamp rows to [8,135] == edge-pad of both z and h.
__global__ __launch_bounds__(256, 3) void ode_rk4_step(
    const float* __restrict__ zsrc, float* __restrict__ zdst,
    const bf16_t* __restrict__ w1f, const float* __restrict__ b1,
    const bf16_t* __restrict__ w2f, const float* __restrict__ b2,
    const float* __restrict__ damp_p)
{
    __shared__ bf16_t ZC[144*64];   // current state (bf16, transposed, swizzled)
    __shared__ bf16_t HT[144*64];   // h = gelu(conv1(state))

    const int tid  = threadIdx.x;
    const int w    = tid >> 6;
    const int lane = tid & 63;
    const int n31  = lane & 31;
    const int g    = lane >> 5;
    const int mtb  = (w & 1) * 32;            // this wave's oc base
    const int b    = blockIdx.y;
    const int l0   = blockIdx.x * NT;
    const size_t bbase = (size_t)b * Cn * Ln;
    const float damp = damp_p[0];
    const int pmin = (blockIdx.x == 0) ? 8 : 0;
    const int pmax = (blockIdx.x == gridDim.x - 1) ? 135 : 143;

    // ---- stage zsrc -> ZC only ----
    for (int cc = 0; cc < 16; ++cc) {
        int c = (w << 4) + cc;
        const float* zr = zsrc + bbase + (size_t)c * Ln;
        #pragma unroll
        for (int m2 = 0; m2 < 3; ++m2) {
            int p = lane + (m2 << 6);
            if (p < 144) {
                int l = l0 - 8 + p;
                l = l < 0 ? 0 : (l > Ln-1 ? Ln-1 : l);
                ZC[p*64 + (c ^ ((p & 7) << 3))] = (bf16_t)zr[l];
            }
        }
    }

    // biases in C-fragment lane order
    float bias1[16], bias2[16];
    #pragma unroll
    for (int r = 0; r < 16; ++r) {
        int oc = mtb + (r&3) + 8*(r>>2) + 4*g;
        bias1[r] = b1[oc];
        bias2[r] = b2[oc];
    }

    float sum[3][16];   // k1 + 2k2 + 2k3, static-indexed only

    __syncthreads();

    #pragma unroll
    for (int i = 0; i < 4; ++i) {
        const int hLo = 2*i + 1, hHi = 143 - 2*i;
        const int kLo = 2*i + 2, kHi = 142 - 2*i;

        // ---- phase A: conv1 -> gelu -> HT ----
        {
            bf16x8 af[12];
            const bf16x8* wp = (const bf16x8*)w1f + ((w & 1) * 12) * 64 + lane;
            #pragma unroll
            for (int f = 0; f < 12; ++f) af[f] = wp[f*64];

            #pragma unroll
            for (int it = 0; it < 3; ++it) {
                int u = w + it*4;
                if (u < 10) {
                    int nt = u >> 1;
                    int ph = nt*32 + n31;
                    f32x16 acc = (f32x16)0.0f;
                    #pragma unroll
                    for (int tau = 0; tau < 3; ++tau) {
                        int p = ph + tau - 1;
                        p = p < pmin ? pmin : (p > pmax ? pmax : p);
                        int e0 = p*64 + ((g*8) ^ ((p & 7) << 3));
                        #pragma unroll
                        for (int ks = 0; ks < 4; ++ks) {
                            bf16x8 bb = *(const bf16x8*)&ZC[e0 ^ (ks*16)];
                            acc = __builtin_amdgcn_mfma_f32_32x32x16_bf16(af[tau*4+ks], bb, acc, 0, 0, 0);
                        }
                    }
                    if (ph >= hLo && ph < hHi) {
                        int qs = (ph & 7) << 3;
                        int qr = ph*64;
                        #pragma unroll
                        for (int t = 0; t < 4; ++t) {
                            bf16x4 hv;
                            #pragma unroll
                            for (int e = 0; e < 4; ++e)
                                hv[e] = (bf16_t)gelu_fast(acc[t*4+e] + bias1[t*4+e]);
                            int oc0 = mtb + t*8 + g*4;
                            *(bf16x4*)&HT[qr + (oc0 ^ qs)] = hv;
                        }
                    }
                }
            }
        }
        __syncthreads();

        // ---- phase B: conv2 -> tanh -> k -> state update / RK4 combine ----
        {
            bf16x8 af[12];
            const bf16x8* wp = (const bf16x8*)w2f + ((w & 1) * 12) * 64 + lane;
            #pragma unroll
            for (int f = 0; f < 12; ++f) af[f] = wp[f*64];

            #pragma unroll
            for (int it = 0; it < 3; ++it) {
                int u = w + it*4;
                if (u < 10) {
                    int nt = u >> 1;
                    int pk = nt*32 + n31;
                    f32x16 acc = (f32x16)0.0f;
                    #pragma unroll
                    for (int tau = 0; tau < 3; ++tau) {
                        int q = pk + tau - 1;
                        q = q < pmin ? pmin : (q > pmax ? pmax : q);
                        int e0 = q*64 + ((g*8) ^ ((q & 7) << 3));
                        #pragma unroll
                        for (int ks = 0; ks < 4; ++ks) {
                            bf16x8 bb = *(const bf16x8*)&HT[e0 ^ (ks*16)];
                            acc = __builtin_amdgcn_mfma_f32_32x32x16_bf16(af[tau*4+ks], bb, acc, 0, 0, 0);
                        }
                    }
                    if (pk >= kLo && pk < kHi) {
                        int gcol = l0 + pk - 8;
                        int gc = gcol < 0 ? 0 : (gcol > Ln-1 ? Ln-1 : gcol);
                        int sw = (pk & 7) << 3;
                        int pr = pk*64;
                        #pragma unroll
                        for (int r = 0; r < 16; ++r) {
                            int ocr = mtb + (r&3) + 8*(r>>2) + 4*g;
                            int e = pr + (ocr ^ sw);
                            float zb_v = zsrc[bbase + (size_t)ocr*Ln + gc];
                            float zin_v = (i == 0) ? zb_v : (float)ZC[e];
                            float kv = tanh_fast(acc[r] + bias2[r]) - damp * zin_v;
                            if (i == 0) {
                                ZC[e] = (bf16_t)(zb_v + 0.05f * kv);
                                sum[it][r] = kv;
                            } else if (i == 1) {
                                ZC[e] = (bf16_t)(zb_v + 0.05f * kv);
                                sum[it][r] += 2.0f * kv;
                            } else if (i == 2) {
                                ZC[e] = (bf16_t)(zb_v + 0.10f * kv);
                                sum[it][r] += 2.0f * kv;
                            } else {
                                zdst[bbase + (size_t)ocr*Ln + gcol] =
                                    zb_v + (0.1f/6.0f) * (sum[it][r] + kv);
                            }
                        }
                    }
                }
            }
        }
        if (i < 3) __syncthreads();
    }
}

// ---------------- per-row mean over L ----------------
__global__ __launch_bounds__(256) void mean_kernel(const float* __restrict__ in, float* __restrict__ m)
{
    const int bc = blockIdx.x;
    const float* __restrict__ row = in + (size_t)bc*Ln;
    float s = 0.0f;
    for (int l = threadIdx.x; l < Ln; l += 256) s += row[l];
    #pragma unroll
    for (int off = 32; off > 0; off >>= 1) s += __shfl_down(s, off, 64);
    __shared__ float red[4];
    if ((threadIdx.x & 63) == 0) red[threadIdx.x >> 6] = s;
    __syncthreads();
    if (threadIdx.x == 0) m[bc] = (red[0]+red[1]+red[2]+red[3]) * (1.0f/Ln);
}

// ---------------- dywan: tiny MLP -> lo/hi + ortho contribution ----------------
__global__ __launch_bounds__(256) void dywan_kernel(
    const float* __restrict__ m,
    const float* __restrict__ stat_w, const float* __restrict__ stat_b,
    const float* __restrict__ gen1_w, const float* __restrict__ gen1_b,
    const float* __restrict__ gen2_w, const float* __restrict__ gen2_b,
    float* __restrict__ tail, int lvl)
{
    __shared__ float m_s[Bn][Cn];
    __shared__ float stat_s[Bn][64];
    __shared__ float g1_s[Bn][128];
    __shared__ float g_s[Bn][16];
    __shared__ float ored[Bn];
    const int tid = threadIdx.x;
    for (int i = tid; i < Bn*Cn; i += 256) m_s[i>>6][i&63] = m[i];
    __syncthreads();
    for (int i = tid; i < Bn*64; i += 256) {
        int b = i >> 6, h = i & 63;
        float a = stat_b[h];
        for (int c = 0; c < Cn; ++c) a = fmaf(stat_w[h*64+c], m_s[b][c], a);
        stat_s[b][h] = 0.5f * a * (1.0f + erff(a * 0.7071067811865476f));
    }
    __syncthreads();
    for (int i = tid; i < Bn*128; i += 256) {
        int b = i >> 7, j = i & 127;
        float a = gen1_b[j];
        for (int h = 0; h < 64; ++h) a = fmaf(gen1_w[j*64+h], stat_s[b][h], a);
        g1_s[b][j] = 0.5f * a * (1.0f + erff(a * 0.7071067811865476f));
    }
    __syncthreads();
    for (int i = tid; i < Bn*16; i += 256) {
        int b = i >> 4, q = i & 15;
        float a = gen2_b[q];
        for (int j = 0; j < 128; ++j) a = fmaf(gen2_w[q*128+j], g1_s[b][j], a);
        g_s[b][q] = a;
    }
    __syncthreads();
    for (int i = tid; i < Bn*16; i += 256) {
        int b = i >> 4, q = i & 15;
        if (q < FLn) tail[1 + lvl*(Bn*FLn) + b*FLn + q] = g_s[b][q];
        else         tail[1 + 3*(Bn*FLn) + lvl*(Bn*FLn) + b*FLn + (q-FLn)] = g_s[b][q];
    }
    if (tid < Bn) {
        const int b = tid;
        float S1 = 0.f, n2 = 0.f, sm = 0.f, prev = 0.f;
        #pragma unroll
        for (int k = 0; k < FLn; ++k) {
            float v = g_s[b][k];
            S1 += fabsf(v); n2 = fmaf(v, v, n2);
            sm += fabsf(v - prev); prev = v;
        }
        sm += fabsf(prev);
        float den = sqrtf(n2) + 1e-8f;
        float Sn = S1 / den;
        float s2n = n2 / (den*den);
        ored[b] = 0.01f * (3.0f*Sn*Sn*(1.0f/2048.0f) + fabsf(s2n - 1.0f)*(1.0f/32.0f))
                + 0.1f * sm * (1.0f/288.0f);
    }
    __syncthreads();
    if (tid == 0) {
        float o = 0.f;
        for (int b = 0; b < Bn; ++b) o += ored[b];
        if (lvl == 0) tail[0] = o; else tail[0] += o;
    }
}

// ---------------- per-batch 8-tap FIR (lo -> new approx, hi -> details) ----------------
__global__ __launch_bounds__(256) void filter_kernel(
    const float* __restrict__ in, float* __restrict__ napprox,
    float* __restrict__ det,
    const float* __restrict__ lo, const float* __restrict__ hi)
{
    const int bc = blockIdx.y;
    const int b = bc >> 6;
    float lov[8], hiv[8];
    #pragma unroll
    for (int k = 0; k < 8; ++k) { lov[k] = lo[b*8+k]; hiv[k] = hi[b*8+k]; }
    const float* __restrict__ row = in + (size_t)bc*Ln;
    const int l = blockIdx.x*256 + threadIdx.x;
    float na = 0.0f, dv = 0.0f;
    #pragma unroll
    for (int k = 0; k < 8; ++k) {
        int j = l + k - 4;
        j = j < 0 ? 0 : (j >= Ln ? Ln-1 : j);
        float v = row[j];
        na = fmaf(v, lov[k], na);
        dv = fmaf(v, hiv[k], dv);
    }
    size_t g = (size_t)bc*Ln + l;
    if (napprox) napprox[g] = na;
    det[g] = dv;
}

// ---------------- reconstruction: att(1x1) + gate(3-conv, zero pad) + updates ----------------
template<bool HAS_ATT>
__global__ __launch_bounds__(256) void stage3_kernel(
    const float* __restrict__ cur_in, float* __restrict__ det,
    float* __restrict__ cur_out,
    const float* __restrict__ gwt, const float* __restrict__ gb,
    const float* __restrict__ aw1, const float* __restrict__ ab1,
    const float* __restrict__ aw2t, const float* __restrict__ ab2)
{
    __shared__ float cur_s[Cn][TILE3+2];
    __shared__ float t1_s[MIDn][TILE3];
    __shared__ float gate_s[Cn][TILE3+1];
    __shared__ float att_s[Cn][TILE3+1];
    const int b  = blockIdx.y;
    const int l0 = blockIdx.x * TILE3;
    const int tid = threadIdx.x;
    const float* __restrict__ cb = cur_in + (size_t)b*Cn*Ln;

    for (int idx = tid; idx < Cn*(TILE3+2); idx += 256) {
        int c = idx / (TILE3+2);
        int j = idx - c*(TILE3+2);
        int l = l0 - 1 + j;
        cur_s[c][j] = (l < 0 || l >= Ln) ? 0.0f : cb[c*Ln + l];
    }
    __syncthreads();

    if (HAS_ATT) {
        for (int i = tid; i < MIDn*TILE3; i += 256) {
            int mm = i / TILE3, t = i - mm*TILE3;
            float a = ab1[mm];
            for (int c = 0; c < Cn; ++c) a = fmaf(aw1[mm*64 + c], cur_s[c][t+1], a);
            t1_s[mm][t] = gelu_fast(a);
        }
        __syncthreads();
    }

    const int oc = tid & 63;
    const int pg = tid >> 6;
    const int t0 = pg*16;
    {
        float gv[16];
        const float bb = gb[oc];
        #pragma unroll
        for (int j = 0; j < 16; ++j) gv[j] = bb;
        for (int c8 = 0; c8 < 64; c8 += 8) {
            float wr[24];
            #pragma unroll
            for (int cc = 0; cc < 8; ++cc) {
                wr[cc*3+0] = gwt[((c8+cc)*3+0)*64 + oc];
                wr[cc*3+1] = gwt[((c8+cc)*3+1)*64 + oc];
                wr[cc*3+2] = gwt[((c8+cc)*3+2)*64 + oc];
            }
            #pragma unroll
            for (int cc = 0; cc < 8; ++cc) {
                const float* cr = &cur_s[c8+cc][t0];
                float x0 = cr[0], x1 = cr[1];
                #pragma unroll
                for (int j = 0; j < 16; ++j) {
                    float x2 = cr[j+2];
                    gv[j] = fmaf(wr[cc*3+0], x0, fmaf(wr[cc*3+1], x1, fmaf(wr[cc*3+2], x2, gv[j])));
                    x0 = x1; x1 = x2;
                }
            }
        }
        #pragma unroll
        for (int j = 0; j < 16; ++j) gate_s[oc][t0+j] = sigmoid_f(gv[j]);
    }
    if (HAS_ATT) {
        float av[16];
        float w2r[16];
        #pragma unroll
        for (int mm = 0; mm < MIDn; ++mm) w2r[mm] = aw2t[mm*64 + oc];
        const float bb = ab2[oc];
        #pragma unroll
        for (int j = 0; j < 16; ++j) av[j] = bb;
        #pragma unroll
        for (int mm = 0; mm < MIDn; ++mm) {
            #pragma unroll
            for (int j = 0; j < 16; ++j) av[j] = fmaf(w2r[mm], t1_s[mm][t0+j], av[j]);
        }
        #pragma unroll
        for (int j = 0; j < 16; ++j) att_s[oc][t0+j] = sigmoid_f(av[j]);
    }
    __syncthreads();

    const size_t gb0 = (size_t)b*Cn*Ln + l0;
    for (int e = tid; e < Cn*TILE3; e += 256) {
        int c = e >> 6, t = e & 63;
        size_t g = gb0 + (size_t)c*Ln + t;
        float d = det[g];
        if (HAS_ATT) { d = d * (1.0f + att_s[c][t]); det[g] = d; }
        cur_out[g] = cur_s[c][t+1] + gate_s[c][t]*d;
    }
}

extern "C" void kernel_launch(void* const* d_in, const int* in_sizes, int n_in,
                              void* d_out, int out_size, void* d_ws, size_t ws_size,
                              hipStream_t stream)
{
    const float* x      = (const float*)d_in[0];
    const float* c1w    = (const float*)d_in[1];
    const float* c1b    = (const float*)d_in[2];
    const float* c2w    = (const float*)d_in[3];
    const float* c2b    = (const float*)d_in[4];
    const float* damp   = (const float*)d_in[5];
    const float* stat_w = (const float*)d_in[6];
    const float* stat_b = (const float*)d_in[7];
    const float* gen1_w = (const float*)d_in[8];
    const float* gen1_b = (const float*)d_in[9];
    const float* gen2_w = (const float*)d_in[10];
    const float* gen2_b = (const float*)d_in[11];
    const float* gate_w = (const float*)d_in[12];
    const float* gate_b = (const float*)d_in[13];
    const float* att_w1 = (const float*)d_in[14];
    const float* att_b1 = (const float*)d_in[15];
    const float* att_w2 = (const float*)d_in[16];
    const float* att_b2 = (const float*)d_in[17];

    float* out = (float*)d_out;
    // workspace: [Z (Nn)] [WSB (Nn)] [gwt 36864][aw2t 2048][m_ws 2048][w1f][w2f]
    float* Z    = (float*)d_ws;
    float* WSB  = Z + Nn;
    float* gwt  = WSB + Nn;
    float* aw2t = gwt + 36864;
    float* m_ws = aw2t + 2048;
    bf16_t* w1f = (bf16_t*)(m_ws + 2048);
    bf16_t* w2f = w1f + 12288;

    float* tail = out + (size_t)4*Nn;

    prep_weights<<<144, 256, 0, stream>>>(c1w, c2w, gate_w, att_w2, w1f, w2f, gwt, aw2t);

    // ODE: 10 fused RK4 steps, ping-pong Z <-> WSB, final state in WSB
    dim3 gOde(Ln/NT, Bn);
    for (int s = 0; s < 10; ++s) {
        const float* src = (s == 0) ? x : ((s & 1) ? Z : WSB);
        float*       dst = (s & 1) ? WSB : Z;
        ode_rk4_step<<<gOde, 256, 0, stream>>>(src, dst, w1f, c1b, w2f, c2b, damp);
    }
    // after loop: s=9 (odd) wrote WSB -> x_evolved = WSB, Z free

    // stage 2: wavelet levels. approx chain: WSB -> Z -> out0 -> (dropped)
    dim3 gFil(Ln/256, Bn*Cn);
    const float* appr_in[3]  = {WSB, Z, out};
    float*       appr_out[3] = {Z, out, nullptr};
    for (int lvl = 0; lvl < 3; ++lvl) {
        mean_kernel<<<Bn*Cn, 256, 0, stream>>>(appr_in[lvl], m_ws);
        dywan_kernel<<<1, 256, 0, stream>>>(m_ws, stat_w, stat_b, gen1_w, gen1_b,
                                            gen2_w, gen2_b, tail, lvl);
        filter_kernel<<<gFil, 256, 0, stream>>>(appr_in[lvl], appr_out[lvl],
            out + (size_t)(1+lvl)*Nn,
            tail + 1 + lvl*(Bn*FLn),
            tail + 1 + 3*(Bn*FLn) + lvl*(Bn*FLn));
    }

    // stage 3: reconstruction. cur chain: WSB -> Z -> WSB -> out0 (final)
    dim3 gS3(Ln/TILE3, Bn);
    stage3_kernel<false><<<gS3, 256, 0, stream>>>(WSB, out + (size_t)3*Nn, Z,
        gwt + 2*12288, gate_b + 2*64, nullptr, nullptr, nullptr, nullptr);
    stage3_kernel<true><<<gS3, 256, 0, stream>>>(Z, out + (size_t)2*Nn, WSB,
        gwt + 1*12288, gate_b + 1*64, att_w1 + 1024, att_b1 + 16, aw2t + 1024, att_b2 + 64);
    stage3_kernel<true><<<gS3, 256, 0, stream>>>(WSB, out + (size_t)1*Nn, out,
        gwt, gate_b, att_w1, att_b1, aw2t, att_b2);
}

// Round 6
// 1638.266 us; speedup vs baseline: 1.2954x; 1.2954x over previous
//
#include <hip/hip_runtime.h>

#define Bn   32
#define Cn   64
#define Ln   4096
#define Nn   (Bn*Cn*Ln)      // 8388608
#define FLn  8
#define MIDn 16
#define TILE3 64
#define NT   128             // ODE output positions per block (tile rows = NT+16)

typedef __bf16 bf16_t;
typedef bf16_t bf16x4 __attribute__((ext_vector_type(4)));
typedef bf16_t bf16x8 __attribute__((ext_vector_type(8)));
typedef float  f32x16 __attribute__((ext_vector_type(16)));

__device__ __forceinline__ float tanh_fast(float x) {
    float ax = fabsf(x);
    float t  = __expf(-2.0f * ax);
    float r  = __fmaf_rn(-2.0f, __fdividef(t, 1.0f + t), 1.0f);
    return copysignf(r, x);
}
__device__ __forceinline__ float gelu_fast(float x) {
    float x3 = x * x * x;
    float u  = 0.7978845608028654f * __fmaf_rn(0.044715f, x3, x);
    return 0.5f * x * (1.0f + tanh_fast(u));
}
__device__ __forceinline__ float sigmoid_f(float x) {
    return 1.0f / (1.0f + __expf(-x));
}

// ---------------- weight prep: MFMA A-frags + gate/att transposes ----------------
__global__ __launch_bounds__(256) void prep_weights(
    const float* __restrict__ w1, const float* __restrict__ w2,
    const float* __restrict__ gw, const float* __restrict__ aw2,
    bf16_t* __restrict__ w1f, bf16_t* __restrict__ w2f,
    float* __restrict__ gwt, float* __restrict__ aw2t)
{
    int idx = blockIdx.x*256 + threadIdx.x;
    if (idx < 1536) {
        int lane = idx & 63;
        int f  = (idx >> 6) % 12;
        int mt = (idx >> 6) / 12;
        int tau = f >> 2, ks = f & 3;
        int oc = mt*32 + (lane & 31);
        int c0 = ks*16 + (lane >> 5)*8;
        #pragma unroll
        for (int e = 0; e < 8; ++e) {
            int c = c0 + e;
            w1f[idx*8 + e] = (bf16_t)w1[oc*192 + c*3 + tau];
            w2f[idx*8 + e] = (bf16_t)w2[oc*192 + c*3 + tau];
        }
    }
    if (idx < 3*64*192) {
        int lvl = idx / 12288, rem = idx % 12288;
        int oc = rem / 192, r = rem % 192;
        gwt[lvl*12288 + r*64 + oc] = gw[idx];
    }
    if (idx < 2*64*16) {
        int lvl = idx / 1024, rem = idx % 1024;
        int oc = rem / 16, mm = rem % 16;
        aw2t[lvl*1024 + mm*64 + oc] = aw2[idx];
    }
}

// ---------------- fused full-RK4-step kernel (v3) ----------------
// LDS: ZC (state), HT (intermediate), Z0 compact rows [8,136) (RK4 base).
// Granule-8 XOR swizzle, b128 fragment reads, packed bf16x4 epilogue I/O.
// Tile coord p in [0,144): l = l0-8+p. Per eval i: h rows [2i+1,143-2i),
// k rows [2i+2,142-2i); outputs p in [8,136). Edge blocks read-clamp to
// [8,135] == edge-pad of z and of the INTERMEDIATE h (reference semantics).
// Halo state cells (p outside [8,136)) take their RK4 base from global zsrc.
__global__ __launch_bounds__(256, 3) void ode_rk4_step(
    const float* __restrict__ zsrc, float* __restrict__ zdst,
    const bf16_t* __restrict__ w1f, const float* __restrict__ b1,
    const bf16_t* __restrict__ w2f, const float* __restrict__ b2,
    const float* __restrict__ damp_p)
{
    __shared__ bf16_t ZC[144*64];   // 18432 B
    __shared__ bf16_t HT[144*64];   // 18432 B
    __shared__ bf16_t Z0[128*64];   // 16384 B  (rows p-8 for p in [8,136))

    const int tid  = threadIdx.x;
    const int w    = tid >> 6;
    const int lane = tid & 63;
    const int n31  = lane & 31;
    const int g    = lane >> 5;
    const int mtb  = (w & 1) * 32;            // this wave's oc base
    const int b    = blockIdx.y;
    const int l0   = blockIdx.x * NT;
    const size_t bbase = (size_t)b * Cn * Ln;
    const float damp = damp_p[0];
    const int pmin = (blockIdx.x == 0) ? 8 : 0;
    const int pmax = (blockIdx.x == gridDim.x - 1) ? 135 : 143;

    // ---- stage zsrc -> ZC (+ Z0 for output rows), packed 4-channel writes ----
    #pragma unroll
    for (int j = 0; j < 4; ++j) {
        const int c0 = (w << 4) + j*4;
        const float* zr0 = zsrc + bbase + (size_t)(c0+0) * Ln;
        const float* zr1 = zsrc + bbase + (size_t)(c0+1) * Ln;
        const float* zr2 = zsrc + bbase + (size_t)(c0+2) * Ln;
        const float* zr3 = zsrc + bbase + (size_t)(c0+3) * Ln;
        #pragma unroll
        for (int m2 = 0; m2 < 3; ++m2) {
            int p = lane + (m2 << 6);
            if (p < 144) {
                int l = l0 - 8 + p;
                l = l < 0 ? 0 : (l > Ln-1 ? Ln-1 : l);
                bf16x4 v;
                v[0] = (bf16_t)zr0[l]; v[1] = (bf16_t)zr1[l];
                v[2] = (bf16_t)zr2[l]; v[3] = (bf16_t)zr3[l];
                int cx = c0 ^ ((p & 7) << 3);
                *(bf16x4*)&ZC[p*64 + cx] = v;
                if (p >= 8 && p < 136) *(bf16x4*)&Z0[(p-8)*64 + cx] = v;
            }
        }
    }

    // biases in C-fragment lane order
    float bias1[16], bias2[16];
    #pragma unroll
    for (int r = 0; r < 16; ++r) {
        int oc = mtb + (r&3) + 8*(r>>2) + 4*g;
        bias1[r] = b1[oc];
        bias2[r] = b2[oc];
    }

    float sum[3][16];   // k1 + 2k2 + 2k3, static-indexed only

    __syncthreads();

    #pragma unroll
    for (int i = 0; i < 4; ++i) {
        const int hLo = 2*i + 1, hHi = 143 - 2*i;
        const int kLo = 2*i + 2, kHi = 142 - 2*i;

        // ---- phase A: conv1 -> gelu -> HT ----
        {
            bf16x8 af[12];
            const bf16x8* wp = (const bf16x8*)w1f + ((w & 1) * 12) * 64 + lane;
            #pragma unroll
            for (int f = 0; f < 12; ++f) af[f] = wp[f*64];

            #pragma unroll
            for (int it = 0; it < 3; ++it) {
                int u = w + it*4;
                if (u < 10) {
                    int nt = u >> 1;
                    int ph = nt*32 + n31;
                    f32x16 acc = (f32x16)0.0f;
                    #pragma unroll
                    for (int tau = 0; tau < 3; ++tau) {
                        int p = ph + tau - 1;
                        p = p < pmin ? pmin : (p > pmax ? pmax : p);
                        int e0 = p*64 + ((g*8) ^ ((p & 7) << 3));
                        #pragma unroll
                        for (int ks = 0; ks < 4; ++ks) {
                            bf16x8 bb = *(const bf16x8*)&ZC[e0 ^ (ks*16)];
                            acc = __builtin_amdgcn_mfma_f32_32x32x16_bf16(af[tau*4+ks], bb, acc, 0, 0, 0);
                        }
                    }
                    if (ph >= hLo && ph < hHi) {
                        int qs = (ph & 7) << 3;
                        int qr = ph*64;
                        #pragma unroll
                        for (int t = 0; t < 4; ++t) {
                            bf16x4 hv;
                            #pragma unroll
                            for (int e = 0; e < 4; ++e)
                                hv[e] = (bf16_t)gelu_fast(acc[t*4+e] + bias1[t*4+e]);
                            int oc0 = mtb + t*8 + g*4;
                            *(bf16x4*)&HT[qr + (oc0 ^ qs)] = hv;
                        }
                    }
                }
            }
        }
        __syncthreads();

        // ---- phase B: conv2 -> tanh -> k -> state update / RK4 combine ----
        {
            bf16x8 af[12];
            const bf16x8* wp = (const bf16x8*)w2f + ((w & 1) * 12) * 64 + lane;
            #pragma unroll
            for (int f = 0; f < 12; ++f) af[f] = wp[f*64];

            #pragma unroll
            for (int it = 0; it < 3; ++it) {
                int u = w + it*4;
                if (u < 10) {
                    int nt = u >> 1;
                    int pk = nt*32 + n31;
                    f32x16 acc = (f32x16)0.0f;
                    #pragma unroll
                    for (int tau = 0; tau < 3; ++tau) {
                        int q = pk + tau - 1;
                        q = q < pmin ? pmin : (q > pmax ? pmax : q);
                        int e0 = q*64 + ((g*8) ^ ((q & 7) << 3));
                        #pragma unroll
                        for (int ks = 0; ks < 4; ++ks) {
                            bf16x8 bb = *(const bf16x8*)&HT[e0 ^ (ks*16)];
                            acc = __builtin_amdgcn_mfma_f32_32x32x16_bf16(af[tau*4+ks], bb, acc, 0, 0, 0);
                        }
                    }
                    if (pk >= kLo && pk < kHi) {
                        const int sw = (pk & 7) << 3;
                        const int pr = pk*64;
                        const int gcol = l0 + pk - 8;
                        if (i < 3) {
                            const bool inZ0 = (pk >= 8) && (pk < 136);
                            int gc = gcol < 0 ? 0 : (gcol > Ln-1 ? Ln-1 : gcol);
                            const float alpha = (i == 2) ? 0.10f : 0.05f;
                            #pragma unroll
                            for (int t = 0; t < 4; ++t) {
                                int oc0 = mtb + t*8 + g*4;
                                int off = pr + (oc0 ^ sw);
                                bf16x4 zp = *(const bf16x4*)&ZC[off];
                                float base[4];
                                if (i == 0) {
                                    #pragma unroll
                                    for (int e = 0; e < 4; ++e) base[e] = (float)zp[e];
                                } else if (inZ0) {
                                    bf16x4 zz = *(const bf16x4*)&Z0[(pk-8)*64 + (oc0 ^ sw)];
                                    #pragma unroll
                                    for (int e = 0; e < 4; ++e) base[e] = (float)zz[e];
                                } else {
                                    #pragma unroll
                                    for (int e = 0; e < 4; ++e)
                                        base[e] = zsrc[bbase + (size_t)(oc0+e)*Ln + gc];
                                }
                                bf16x4 wv;
                                #pragma unroll
                                for (int e = 0; e < 4; ++e) {
                                    int r = t*4 + e;
                                    float kv = tanh_fast(acc[r] + bias2[r]) - damp * (float)zp[e];
                                    if (i == 0) sum[it][r] = kv;
                                    else        sum[it][r] += 2.0f * kv;
                                    wv[e] = (bf16_t)(base[e] + alpha * kv);
                                }
                                *(bf16x4*)&ZC[off] = wv;
                            }
                        } else {
                            #pragma unroll
                            for (int t = 0; t < 4; ++t) {
                                int oc0 = mtb + t*8 + g*4;
                                int off = pr + (oc0 ^ sw);
                                bf16x4 zp = *(const bf16x4*)&ZC[off];
                                #pragma unroll
                                for (int e = 0; e < 4; ++e) {
                                    int r = t*4 + e;
                                    float kv = tanh_fast(acc[r] + bias2[r]) - damp * (float)zp[e];
                                    size_t gof = bbase + (size_t)(oc0+e)*Ln + gcol;
                                    zdst[gof] = zsrc[gof] + (0.1f/6.0f) * (sum[it][r] + kv);
                                }
                            }
                        }
                    }
                }
            }
        }
        if (i < 3) __syncthreads();
    }
}

// ---------------- per-row mean over L ----------------
__global__ __launch_bounds__(256) void mean_kernel(const float* __restrict__ in, float* __restrict__ m)
{
    const int bc = blockIdx.x;
    const float* __restrict__ row = in + (size_t)bc*Ln;
    float s = 0.0f;
    for (int l = threadIdx.x; l < Ln; l += 256) s += row[l];
    #pragma unroll
    for (int off = 32; off > 0; off >>= 1) s += __shfl_down(s, off, 64);
    __shared__ float red[4];
    if ((threadIdx.x & 63) == 0) red[threadIdx.x >> 6] = s;
    __syncthreads();
    if (threadIdx.x == 0) m[bc] = (red[0]+red[1]+red[2]+red[3]) * (1.0f/Ln);
}

// ---------------- dywan: tiny MLP -> lo/hi + ortho contribution ----------------
__global__ __launch_bounds__(256) void dywan_kernel(
    const float* __restrict__ m,
    const float* __restrict__ stat_w, const float* __restrict__ stat_b,
    const float* __restrict__ gen1_w, const float* __restrict__ gen1_b,
    const float* __restrict__ gen2_w, const float* __restrict__ gen2_b,
    float* __restrict__ tail, int lvl)
{
    __shared__ float m_s[Bn][Cn];
    __shared__ float stat_s[Bn][64];
    __shared__ float g1_s[Bn][128];
    __shared__ float g_s[Bn][16];
    __shared__ float ored[Bn];
    const int tid = threadIdx.x;
    for (int i = tid; i < Bn*Cn; i += 256) m_s[i>>6][i&63] = m[i];
    __syncthreads();
    for (int i = tid; i < Bn*64; i += 256) {
        int b = i >> 6, h = i & 63;
        float a = stat_b[h];
        for (int c = 0; c < Cn; ++c) a = fmaf(stat_w[h*64+c], m_s[b][c], a);
        stat_s[b][h] = 0.5f * a * (1.0f + erff(a * 0.7071067811865476f));
    }
    __syncthreads();
    for (int i = tid; i < Bn*128; i += 256) {
        int b = i >> 7, j = i & 127;
        float a = gen1_b[j];
        for (int h = 0; h < 64; ++h) a = fmaf(gen1_w[j*64+h], stat_s[b][h], a);
        g1_s[b][j] = 0.5f * a * (1.0f + erff(a * 0.7071067811865476f));
    }
    __syncthreads();
    for (int i = tid; i < Bn*16; i += 256) {
        int b = i >> 4, q = i & 15;
        float a = gen2_b[q];
        for (int j = 0; j < 128; ++j) a = fmaf(gen2_w[q*128+j], g1_s[b][j], a);
        g_s[b][q] = a;
    }
    __syncthreads();
    for (int i = tid; i < Bn*16; i += 256) {
        int b = i >> 4, q = i & 15;
        if (q < FLn) tail[1 + lvl*(Bn*FLn) + b*FLn + q] = g_s[b][q];
        else         tail[1 + 3*(Bn*FLn) + lvl*(Bn*FLn) + b*FLn + (q-FLn)] = g_s[b][q];
    }
    if (tid < Bn) {
        const int b = tid;
        float S1 = 0.f, n2 = 0.f, sm = 0.f, prev = 0.f;
        #pragma unroll
        for (int k = 0; k < FLn; ++k) {
            float v = g_s[b][k];
            S1 += fabsf(v); n2 = fmaf(v, v, n2);
            sm += fabsf(v - prev); prev = v;
        }
        sm += fabsf(prev);
        float den = sqrtf(n2) + 1e-8f;
        float Sn = S1 / den;
        float s2n = n2 / (den*den);
        ored[b] = 0.01f * (3.0f*Sn*Sn*(1.0f/2048.0f) + fabsf(s2n - 1.0f)*(1.0f/32.0f))
                + 0.1f * sm * (1.0f/288.0f);
    }
    __syncthreads();
    if (tid == 0) {
        float o = 0.f;
        for (int b = 0; b < Bn; ++b) o += ored[b];
        if (lvl == 0) tail[0] = o; else tail[0] += o;
    }
}

// ---------------- per-batch 8-tap FIR (lo -> new approx, hi -> details) ----------------
__global__ __launch_bounds__(256) void filter_kernel(
    const float* __restrict__ in, float* __restrict__ napprox,
    float* __restrict__ det,
    const float* __restrict__ lo, const float* __restrict__ hi)
{
    const int bc = blockIdx.y;
    const int b = bc >> 6;
    float lov[8], hiv[8];
    #pragma unroll
    for (int k = 0; k < 8; ++k) { lov[k] = lo[b*8+k]; hiv[k] = hi[b*8+k]; }
    const float* __restrict__ row = in + (size_t)bc*Ln;
    const int l = blockIdx.x*256 + threadIdx.x;
    float na = 0.0f, dv = 0.0f;
    #pragma unroll
    for (int k = 0; k < 8; ++k) {
        int j = l + k - 4;
        j = j < 0 ? 0 : (j >= Ln ? Ln-1 : j);
        float v = row[j];
        na = fmaf(v, lov[k], na);
        dv = fmaf(v, hiv[k], dv);
    }
    size_t g = (size_t)bc*Ln + l;
    if (napprox) napprox[g] = na;
    det[g] = dv;
}

// ---------------- reconstruction: att(1x1) + gate(3-conv, zero pad) + updates ----------------
template<bool HAS_ATT>
__global__ __launch_bounds__(256) void stage3_kernel(
    const float* __restrict__ cur_in, float* __restrict__ det,
    float* __restrict__ cur_out,
    const float* __restrict__ gwt, const float* __restrict__ gb,
    const float* __restrict__ aw1, const float* __restrict__ ab1,
    const float* __restrict__ aw2t, const float* __restrict__ ab2)
{
    __shared__ float cur_s[Cn][TILE3+2];
    __shared__ float t1_s[MIDn][TILE3];
    __shared__ float gate_s[Cn][TILE3+1];
    __shared__ float att_s[Cn][TILE3+1];
    const int b  = blockIdx.y;
    const int l0 = blockIdx.x * TILE3;
    const int tid = threadIdx.x;
    const float* __restrict__ cb = cur_in + (size_t)b*Cn*Ln;

    for (int idx = tid; idx < Cn*(TILE3+2); idx += 256) {
        int c = idx / (TILE3+2);
        int j = idx - c*(TILE3+2);
        int l = l0 - 1 + j;
        cur_s[c][j] = (l < 0 || l >= Ln) ? 0.0f : cb[c*Ln + l];
    }
    __syncthreads();

    if (HAS_ATT) {
        for (int i = tid; i < MIDn*TILE3; i += 256) {
            int mm = i / TILE3, t = i - mm*TILE3;
            float a = ab1[mm];
            for (int c = 0; c < Cn; ++c) a = fmaf(aw1[mm*64 + c], cur_s[c][t+1], a);
            t1_s[mm][t] = gelu_fast(a);
        }
        __syncthreads();
    }

    const int oc = tid & 63;
    const int pg = tid >> 6;
    const int t0 = pg*16;
    {
        float gv[16];
        const float bb = gb[oc];
        #pragma unroll
        for (int j = 0; j < 16; ++j) gv[j] = bb;
        for (int c8 = 0; c8 < 64; c8 += 8) {
            float wr[24];
            #pragma unroll
            for (int cc = 0; cc < 8; ++cc) {
                wr[cc*3+0] = gwt[((c8+cc)*3+0)*64 + oc];
                wr[cc*3+1] = gwt[((c8+cc)*3+1)*64 + oc];
                wr[cc*3+2] = gwt[((c8+cc)*3+2)*64 + oc];
            }
            #pragma unroll
            for (int cc = 0; cc < 8; ++cc) {
                const float* cr = &cur_s[c8+cc][t0];
                float x0 = cr[0], x1 = cr[1];
                #pragma unroll
                for (int j = 0; j < 16; ++j) {
                    float x2 = cr[j+2];
                    gv[j] = fmaf(wr[cc*3+0], x0, fmaf(wr[cc*3+1], x1, fmaf(wr[cc*3+2], x2, gv[j])));
                    x0 = x1; x1 = x2;
                }
            }
        }
        #pragma unroll
        for (int j = 0; j < 16; ++j) gate_s[oc][t0+j] = sigmoid_f(gv[j]);
    }
    if (HAS_ATT) {
        float av[16];
        float w2r[16];
        #pragma unroll
        for (int mm = 0; mm < MIDn; ++mm) w2r[mm] = aw2t[mm*64 + oc];
        const float bb = ab2[oc];
        #pragma unroll
        for (int j = 0; j < 16; ++j) av[j] = bb;
        #pragma unroll
        for (int mm = 0; mm < MIDn; ++mm) {
            #pragma unroll
            for (int j = 0; j < 16; ++j) av[j] = fmaf(w2r[mm], t1_s[mm][t0+j], av[j]);
        }
        #pragma unroll
        for (int j = 0; j < 16; ++j) att_s[oc][t0+j] = sigmoid_f(av[j]);
    }
    __syncthreads();

    const size_t gb0 = (size_t)b*Cn*Ln + l0;
    for (int e = tid; e < Cn*TILE3; e += 256) {
        int c = e >> 6, t = e & 63;
        size_t g = gb0 + (size_t)c*Ln + t;
        float d = det[g];
        if (HAS_ATT) { d = d * (1.0f + att_s[c][t]); det[g] = d; }
        cur_out[g] = cur_s[c][t+1] + gate_s[c][t]*d;
    }
}

extern "C" void kernel_launch(void* const* d_in, const int* in_sizes, int n_in,
                              void* d_out, int out_size, void* d_ws, size_t ws_size,
                              hipStream_t stream)
{
    const float* x      = (const float*)d_in[0];
    const float* c1w    = (const float*)d_in[1];
    const float* c1b    = (const float*)d_in[2];
    const float* c2w    = (const float*)d_in[3];
    const float* c2b    = (const float*)d_in[4];
    const float* damp   = (const float*)d_in[5];
    const float* stat_w = (const float*)d_in[6];
    const float* stat_b = (const float*)d_in[7];
    const float* gen1_w = (const float*)d_in[8];
    const float* gen1_b = (const float*)d_in[9];
    const float* gen2_w = (const float*)d_in[10];
    const float* gen2_b = (const float*)d_in[11];
    const float* gate_w = (const float*)d_in[12];
    const float* gate_b = (const float*)d_in[13];
    const float* att_w1 = (const float*)d_in[14];
    const float* att_b1 = (const float*)d_in[15];
    const float* att_w2 = (const float*)d_in[16];
    const float* att_b2 = (const float*)d_in[17];

    float* out = (float*)d_out;
    // workspace: [Z (Nn)] [WSB (Nn)] [gwt 36864][aw2t 2048][m_ws 2048][w1f][w2f]
    float* Z    = (float*)d_ws;
    float* WSB  = Z + Nn;
    float* gwt  = WSB + Nn;
    float* aw2t = gwt + 36864;
    float* m_ws = aw2t + 2048;
    bf16_t* w1f = (bf16_t*)(m_ws + 2048);
    bf16_t* w2f = w1f + 12288;

    float* tail = out + (size_t)4*Nn;

    prep_weights<<<144, 256, 0, stream>>>(c1w, c2w, gate_w, att_w2, w1f, w2f, gwt, aw2t);

    // ODE: 10 fused RK4 steps, ping-pong Z <-> WSB, final state in WSB
    dim3 gOde(Ln/NT, Bn);
    for (int s = 0; s < 10; ++s) {
        const float* src = (s == 0) ? x : ((s & 1) ? Z : WSB);
        float*       dst = (s & 1) ? WSB : Z;
        ode_rk4_step<<<gOde, 256, 0, stream>>>(src, dst, w1f, c1b, w2f, c2b, damp);
    }
    // after loop: s=9 (odd) wrote WSB -> x_evolved = WSB, Z free

    // stage 2: wavelet levels. approx chain: WSB -> Z -> out0 -> (dropped)
    dim3 gFil(Ln/256, Bn*Cn);
    const float* appr_in[3]  = {WSB, Z, out};
    float*       appr_out[3] = {Z, out, nullptr};
    for (int lvl = 0; lvl < 3; ++lvl) {
        mean_kernel<<<Bn*Cn, 256, 0, stream>>>(appr_in[lvl], m_ws);
        dywan_kernel<<<1, 256, 0, stream>>>(m_ws, stat_w, stat_b, gen1_w, gen1_b,
                                            gen2_w, gen2_b, tail, lvl);
        filter_kernel<<<gFil, 256, 0, stream>>>(appr_in[lvl], appr_out[lvl],
            out + (size_t)(1+lvl)*Nn,
            tail + 1 + lvl*(Bn*FLn),
            tail + 1 + 3*(Bn*FLn) + lvl*(Bn*FLn));
    }

    // stage 3: reconstruction. cur chain: WSB -> Z -> WSB -> out0 (final)
    dim3 gS3(Ln/TILE3, Bn);
    stage3_kernel<false><<<gS3, 256, 0, stream>>>(WSB, out + (size_t)3*Nn, Z,
        gwt + 2*12288, gate_b + 2*64, nullptr, nullptr, nullptr, nullptr);
    stage3_kernel<true><<<gS3, 256, 0, stream>>>(Z, out + (size_t)2*Nn, WSB,
        gwt + 1*12288, gate_b + 1*64, att_w1 + 1024, att_b1 + 16, aw2t + 1024, att_b2 + 64);
    stage3_kernel<true><<<gS3, 256, 0, stream>>>(WSB, out + (size_t)1*Nn, out,
        gwt, gate_b, att_w1, att_b1, aw2t, att_b2);
}